// Round 5
// baseline (256.005 us; speedup 1.0000x reference)
//
#include <hip/hip_runtime.h>

// Problem constants
static constexpr int Nn_ = 32, Cc_ = 64, Hh_ = 64, Ww_ = 64;
static constexpr int K_ = 512;
static constexpr int HW_ = Hh_ * Ww_;             // 4096
static constexpr int CHW_ = Cc_ * HW_;            // 262144
static constexpr int T_ = Nn_ * Hh_ * Ww_;        // 131072 tokens
static constexpr int OUT_ELEMS = Nn_ * Cc_ * Hh_ * Ww_;  // 8388608
// d_out layout: [out][codebook_new (32768)][N_new (512)][m_new (32768)]
static constexpr int OFF_CB = OUT_ELEMS;
static constexpr int OFF_N  = OUT_ELEMS + 32768;
static constexpr int OFF_M  = OUT_ELEMS + 32768 + 512;

// ws layout (float indices):
// [0, 33280)            merged accumulator [psum 512*64][pcnt 512]
// [33280]               fixcnt (int)
// [33284, +131072)      fixlist (int token ids)
// [WS_CBH, +16384)      cb hi fp16 [512][64]
// [WS_CBL, +16384)      cb lo fp16 [512][64]
// [WS_CN,  +512)        cnorm fp32
// [WS_CNA, +512)        cnorm re-ordered for MFMA fold: [hi][tile][reg]
static constexpr int WS_ACC     = 0;
static constexpr int ACC_CNT    = 32768;
static constexpr int ACC_F      = K_ * Cc_ + K_;  // 33280
static constexpr int WS_FIXCNT  = 33280;
static constexpr int WS_FIXLIST = 33284;
static constexpr int WS_CBH     = WS_FIXLIST + T_;        // 164356 (16B-aligned)
static constexpr int WS_CBL     = WS_CBH + 16384;         // 180740
static constexpr int WS_CN      = WS_CBL + 16384;         // 197124
static constexpr int WS_CNA     = WS_CN + 512;            // 197636

static constexpr float THETA = 0.015f;  // certification threshold (>= 2x worst
                                        // realistic fp16x3 error incl denorm flush)

typedef _Float16 half8  __attribute__((ext_vector_type(8)));
typedef float    f32x16 __attribute__((ext_vector_type(16)));

// K0: zero accumulator + fixcnt each replay (graph-safe).
__global__ __launch_bounds__(256) void k_zero(float* __restrict__ ws) {
    int i = blockIdx.x * 256 + threadIdx.x;
    if (i < 8321) ((float4*)ws)[i] = make_float4(0.f, 0.f, 0.f, 0.f);
}

// KP: split codebook into fp16 hi/lo, compute cnorm (fp32) + the MFMA-fold
// reordering cnA[hi][tile][reg] = cnorm[32*tile + (reg&3)+8*(reg>>2) + 4*hi].
__global__ __launch_bounds__(256) void k_prep(const float* __restrict__ cb,
                                              float* __restrict__ ws) {
    int j = blockIdx.x * 256 + threadIdx.x;   // 0..32767; wave == one cb row
    float v = cb[j];
    _Float16 h = (_Float16)v;
    _Float16 lo = (_Float16)(v - (float)h);
    ((_Float16*)(ws + WS_CBH))[j] = h;
    ((_Float16*)(ws + WS_CBL))[j] = lo;
    float sq = v * v;
#pragma unroll
    for (int m = 1; m < 64; m <<= 1) sq += __shfl_xor(sq, m);
    if ((threadIdx.x & 63) == 0) {
        int k = j >> 6;
        ws[WS_CN + k] = sq;
        int t = k >> 5, r5 = k & 31;
        int hi = (r5 >> 2) & 1;
        int reg = (r5 & 3) + 4 * (r5 >> 3);
        ws[WS_CNA + hi * 256 + t * 16 + reg] = sq;
    }
}

// K1: fp16x3 split MFMA assign (hh + hl + lh in fp32 acc; lo*lo dropped,
// bounded by THETA-certification; uncertified tokens -> exact k_fix).
// Per block: 128 tokens (rows 2b,2b+1), 4 waves x 32 tokens, 16 cw-tiles of
// 32, 12 MFMAs (32x32x16_f16) per tile. C layout (HW-verified): col=lane&31
// (token), row=(reg&3)+8*(reg>>2)+4*(lane>>5) (cw) -> argmin is lane-local
// + one shfl_xor(32) merge. Within-lane scan order is k-ascending (row
// pattern monotone in reg) -> strict < == np.argmin first-min. K-lane
// mapping uncertainty cancels (same permutation on A and B fragments).
// LDS x-tile: fp16 hi/lo [128][64], 128B rows, XOR-block swizzle
// (blk = c8 ^ (row>>2 & 7)) -> both the stride-4-row b128 stage writes and
// the fragment reads hit the 8-access/bank minimum (no conflicts).
// Epilogues (R4-validated): wave-wide consecutive global atomics for stats
// (certified tokens only), qt-transpose bulk out-write (approx k for
// uncertified, overwritten by k_fix).
__global__ __launch_bounds__(256, 4) void k_assign(const float* __restrict__ x,
                                                   const float* __restrict__ cb,
                                                   float* __restrict__ ws,
                                                   float* __restrict__ out) {
    __shared__ alignas(16) unsigned char smem[35840];
    // [0,16384) xs_h | [16384,32768) xs_l | [32768,34816) cnA
    // [34816,35328) bi_s | [35328,35840) cert_s ; qt overlays [0,33792)
    int* bi_s   = (int*)(smem + 34816);
    int* cert_s = (int*)(smem + 35328);

    const int b    = blockIdx.x;
    const int tid  = threadIdx.x;
    const int lane = tid & 63;
    const int wv   = tid >> 6;
    const int row0 = 2 * b, row1 = 2 * b + 1;
    const int xb0 = (row0 >> 6) * CHW_ + (row0 & 63) * Ww_;
    const int xb1 = (row1 >> 6) * CHW_ + (row1 & 63) * Ww_;

    // ---- stage x -> fp16 hi/lo LDS tile (swizzled) ----
    {
        const int s  = tid & 31;        // token-quad id
        const int c8 = tid >> 5;        // channel octet
        const int r  = s >> 4, wq = s & 15;
        half8 hp[4], lp[4];
#pragma unroll
        for (int stp = 0; stp < 8; ++stp) {
            int ch = c8 * 8 + stp;
            float4 v = *(const float4*)(x + (r ? xb1 : xb0) + ch * HW_ + 4 * wq);
            float vv[4] = {v.x, v.y, v.z, v.w};
#pragma unroll
            for (int j = 0; j < 4; ++j) {
                _Float16 h = (_Float16)vv[j];
                _Float16 lo = (_Float16)(vv[j] - (float)h);
                hp[j][stp] = h; lp[j][stp] = lo;
            }
        }
        const int blk = c8 ^ (wq & 7);
#pragma unroll
        for (int j = 0; j < 4; ++j) {
            int tt = 64 * r + 4 * wq + j;
            *(half8*)(smem + tt * 128 + blk * 16) = hp[j];
            *(half8*)(smem + 16384 + tt * 128 + blk * 16) = lp[j];
        }
        // cnA -> LDS (512 floats)
        ((float*)(smem + 32768))[tid]       = ws[WS_CNA + tid];
        ((float*)(smem + 32768))[tid + 256] = ws[WS_CNA + tid + 256];
    }
    __syncthreads();

    // ---- per-wave B-fragments (x), loaded once ----
    const int tb = 32 * wv + (lane & 31);   // local token of this lane
    const int hi = lane >> 5;
    half8 bh[4], bl[4];
    {
        const int tsw = (tb >> 2) & 7;
#pragma unroll
        for (int ks = 0; ks < 4; ++ks) {
            int blk = (2 * ks + hi) ^ tsw;
            bh[ks] = *(const half8*)(smem + tb * 128 + blk * 16);
            bl[ks] = *(const half8*)(smem + 16384 + tb * 128 + blk * 16);
        }
    }

    // ---- main loop: 16 cw-tiles ----
    const _Float16* __restrict__ cbh = (const _Float16*)(ws + WS_CBH);
    const _Float16* __restrict__ cbl = (const _Float16*)(ws + WS_CBL);
    const float* cnA = (const float*)(smem + 32768);
    float bd1 = __int_as_float(0x7f800000);
    float bd2 = __int_as_float(0x7f800000);
    int bk1 = 0;

#pragma unroll 1
    for (int t = 0; t < 16; ++t) {
        const _Float16* ab = cbh + (t * 32 + (lane & 31)) * 64 + 8 * hi;
        const _Float16* lb = cbl + (t * 32 + (lane & 31)) * 64 + 8 * hi;
        half8 ah[4], al[4];
#pragma unroll
        for (int ks = 0; ks < 4; ++ks) {
            ah[ks] = *(const half8*)(ab + ks * 16);
            al[ks] = *(const half8*)(lb + ks * 16);
        }
        f32x16 acc = {0.f,0.f,0.f,0.f, 0.f,0.f,0.f,0.f,
                      0.f,0.f,0.f,0.f, 0.f,0.f,0.f,0.f};
#pragma unroll
        for (int ks = 0; ks < 4; ++ks) {
            acc = __builtin_amdgcn_mfma_f32_32x32x16_f16(ah[ks], bh[ks], acc, 0, 0, 0);
            acc = __builtin_amdgcn_mfma_f32_32x32x16_f16(ah[ks], bl[ks], acc, 0, 0, 0);
            acc = __builtin_amdgcn_mfma_f32_32x32x16_f16(al[ks], bh[ks], acc, 0, 0, 0);
        }
        float cnv[16];
        {
            const float* cnp = cnA + hi * 256 + t * 16;   // broadcast reads
            *(float4*)&cnv[0]  = *(const float4*)(cnp);
            *(float4*)&cnv[4]  = *(const float4*)(cnp + 4);
            *(float4*)&cnv[8]  = *(const float4*)(cnp + 8);
            *(float4*)&cnv[12] = *(const float4*)(cnp + 12);
        }
        const int tb16 = t << 4;
#pragma unroll
        for (int j = 0; j < 16; ++j) {
            float d = fmaf(-2.0f, acc[j], cnv[j]);
            int kid = tb16 | j;                 // k-order-consistent packed id
            bool lt = d < bd1;
            bd2 = lt ? bd1 : fminf(bd2, d);
            bk1 = lt ? kid : bk1;
            bd1 = fminf(bd1, d);
        }
    }

    // ---- decode + cross-lane (l ^ 32) merge; lanes<32 publish ----
    {
        int t0 = bk1 >> 4, j0 = bk1 & 15;
        int rk = 32 * t0 + (j0 & 3) + 8 * (j0 >> 2) + 4 * hi;
        unsigned uf = __float_as_uint(bd1);
        uf = (uf & 0x80000000u) ? ~uf : (uf | 0x80000000u);
        unsigned long long me = ((unsigned long long)uf << 32) | (unsigned)rk;
        unsigned long long ot = (unsigned long long)__shfl_xor((long long)me, 32);
        float od1 = __shfl_xor(bd1, 32);
        float od2 = __shfl_xor(bd2, 32);
        unsigned long long m1 = (me < ot) ? me : ot;
        float d1m = fminf(bd1, od1);
        float d2m = fminf(fminf(bd2, od2), fmaxf(bd1, od1));
        if (hi == 0) {
            int k1 = (int)(m1 & 0xffffffffu);
            bool cert = (d2m - d1m) > THETA;
            bi_s[tb] = k1;
            cert_s[tb] = cert ? 1 : 0;
            if (!cert) {
                int pos = atomicAdd((int*)(ws + WS_FIXCNT), 1);
                ((int*)(ws + WS_FIXLIST))[pos] = 128 * b + tb;   // global token id
            }
        }
    }
    __syncthreads();   // bi_s/cert_s visible; all fragment reads of xs done

    // ---- fused stats (R4 shape): certified tokens only ----
    float* acc_g = ws + WS_ACC;
#pragma unroll 4
    for (int jj = 0; jj < 32; ++jj) {
        int tt = wv * 32 + jj;
        if (cert_s[tt]) {
            int blkS = (lane >> 3) ^ ((tt >> 2) & 7);
            float xh = (float)*(const _Float16*)(smem + tt * 128 + blkS * 16 + (lane & 7) * 2);
            float xl = (float)*(const _Float16*)(smem + 16384 + tt * 128 + blkS * 16 + (lane & 7) * 2);
            atomicAdd(acc_g + bi_s[tt] * 64 + lane, xh + xl);
        }
    }
    if (tid < 128 && cert_s[tid]) atomicAdd(acc_g + ACC_CNT + bi_s[tid], 1.0f);
    __syncthreads();   // xs reads done before qt overlay

    // ---- q gather + transpose + bulk out write (R4-validated) ----
    float (*qt)[132] = (float(*)[132])smem;
#pragma unroll
    for (int jj = 0; jj < 32; ++jj) {
        int tt = wv * 32 + jj;
        qt[lane][tt] = cb[bi_s[tt] * 64 + lane];
    }
    __syncthreads();
#pragma unroll
    for (int r = 0; r < 2; ++r)
#pragma unroll
        for (int j = 0; j < 16; ++j) {
            int c = wv * 16 + j;
            out[(r ? xb1 : xb0) + c * HW_ + lane] = qt[c][64 * r + lane];
        }
}

// KF: exact fp32 rescan for uncertified tokens. One wave per token; lane
// handles cw {lane, lane+64, ...} (k-ascending in-lane; u64 pack cross-lane
// == np.argmin first-min). Patches out + stats for its tokens.
__global__ __launch_bounds__(256) void k_fix(const float* __restrict__ x,
                                             const float* __restrict__ cb,
                                             float* __restrict__ ws,
                                             float* __restrict__ out) {
    __shared__ float xw[4][64];
    const int tid = threadIdx.x, wv = tid >> 6, lane = tid & 63;
    const int cnt = *(const int*)(ws + WS_FIXCNT);
    const int* list = (const int*)(ws + WS_FIXLIST);

    for (int it = blockIdx.x * 4 + wv; it < cnt; it += 128 * 4) {
        int g = list[it];
        int n = g >> 12, hw = g & 4095;
        const float* xp = x + n * CHW_ + hw;
        float xv = xp[lane * HW_];
        xw[wv][lane] = xv;
        unsigned long long best = ~0ull;
#pragma unroll 1
        for (int jj = 0; jj < 8; ++jj) {
            int k = lane + 64 * jj;
            const float4* cr = (const float4*)(cb + k * 64);
            float dot = 0.f;
#pragma unroll
            for (int q = 0; q < 16; ++q) {
                float4 cv = cr[q];
                dot = fmaf(cv.x, xw[wv][4 * q + 0], dot);
                dot = fmaf(cv.y, xw[wv][4 * q + 1], dot);
                dot = fmaf(cv.z, xw[wv][4 * q + 2], dot);
                dot = fmaf(cv.w, xw[wv][4 * q + 3], dot);
            }
            float d = fmaf(-2.0f, dot, ws[WS_CN + k]);
            unsigned uf = __float_as_uint(d);
            uf = (uf & 0x80000000u) ? ~uf : (uf | 0x80000000u);
            unsigned long long cd = ((unsigned long long)uf << 32) | (unsigned)k;
            if (cd < best) best = cd;
        }
#pragma unroll
        for (int m = 1; m < 64; m <<= 1) {
            unsigned long long o = (unsigned long long)__shfl_xor((long long)best, m);
            if (o < best) best = o;
        }
        int k1 = (int)(best & 0xffffffffu);
        out[n * CHW_ + lane * HW_ + hw] = cb[k1 * 64 + lane];
        atomicAdd(ws + WS_ACC + k1 * 64 + lane, xw[wv][lane]);
        if (lane == 0) atomicAdd(ws + WS_ACC + ACC_CNT + k1, 1.0f);
    }
}

// K3: finalize EMA states + codebook_new from the 133KB merged accumulator.
__global__ __launch_bounds__(256) void k_final(const float* __restrict__ Ns,
                                               const float* __restrict__ ms,
                                               const float* __restrict__ ws,
                                               float* __restrict__ out) {
    int i = blockIdx.x * 256 + threadIdx.x;   // 0..32767
    int k = i >> 6, c = i & 63;

    const float* acc = ws + WS_ACC;
    float s   = acc[i];
    float cnt = acc[ACC_CNT + k];

    const float gamma = 0.99f;
    const float omg   = (float)(1.0 - 0.99);

    bool occ = cnt > 0.0f;
    float Nv = Ns[k];
    float Nnew = occ ? (Nv * gamma + cnt * omg) : Nv;

    float mv = ms[i];
    float mnew = occ ? (mv * gamma + s * omg) : mv;

    out[OFF_CB + i] = mnew / Nnew;
    out[OFF_M  + i] = mnew;
    if (c == 0) out[OFF_N + k] = Nnew;
}

extern "C" void kernel_launch(void* const* d_in, const int* in_sizes, int n_in,
                              void* d_out, int out_size, void* d_ws, size_t ws_size,
                              hipStream_t stream) {
    const float* x  = (const float*)d_in[0];
    const float* cb = (const float*)d_in[1];
    const float* Ns = (const float*)d_in[2];
    const float* ms = (const float*)d_in[3];
    float* out = (float*)d_out;
    float* ws  = (float*)d_ws;

    hipLaunchKernelGGL(k_zero,   dim3(33),   dim3(256), 0, stream, ws);
    hipLaunchKernelGGL(k_prep,   dim3(128),  dim3(256), 0, stream, cb, ws);
    hipLaunchKernelGGL(k_assign, dim3(1024), dim3(256), 0, stream, x, cb, ws, out);
    hipLaunchKernelGGL(k_fix,    dim3(128),  dim3(256), 0, stream, x, cb, ws, out);
    hipLaunchKernelGGL(k_final,  dim3(128),  dim3(256), 0, stream, Ns, ms, ws, out);
}

// Round 6
// 211.672 us; speedup vs baseline: 1.2094x; 1.2094x over previous
//
#include <hip/hip_runtime.h>

// Problem constants
static constexpr int Nn_ = 32, Cc_ = 64, Hh_ = 64, Ww_ = 64;
static constexpr int K_ = 512;
static constexpr int HW_ = Hh_ * Ww_;             // 4096
static constexpr int CHW_ = Cc_ * HW_;            // 262144
static constexpr int T_ = Nn_ * Hh_ * Ww_;        // 131072 tokens
static constexpr int OUT_ELEMS = Nn_ * Cc_ * Hh_ * Ww_;  // 8388608
// d_out layout: [out][codebook_new (32768)][N_new (512)][m_new (32768)]
static constexpr int OFF_CB = OUT_ELEMS;
static constexpr int OFF_N  = OUT_ELEMS + 32768;
static constexpr int OFF_M  = OUT_ELEMS + 32768 + 512;

// ws layout (float indices). NO persistent accumulators -> nothing to zero.
// [WS_IDX, +T)        idx per token (int), k_assign writes, k_fix corrects
// [WS_FIXCNT]         fix counter (int, zeroed by k_prep each replay)
// [WS_FIXLIST, +T)    uncertified token ids
// [WS_CBH/CBL]        cb hi/lo fp16 [512][64]
// [WS_CN/CNA]         cnorm fp32 + MFMA-fold reorder
// [WS_PART, P*33280)  P exclusive dense partials [psum 512*64][pcnt 512]
static constexpr int WS_IDX     = 0;
static constexpr int WS_FIXCNT  = T_;                     // 131072
static constexpr int WS_FIXLIST = T_ + 1;                 // 131073
static constexpr int WS_CBH     = 262148;                 // 16B aligned
static constexpr int WS_CBL     = WS_CBH + 16384;         // 278532
static constexpr int WS_CN      = WS_CBL + 16384;         // 294916
static constexpr int WS_CNA     = WS_CN + 512;            // 295428
static constexpr int WS_PART    = 295940;                 // 16B aligned
static constexpr int SLICE_F    = K_ * Cc_ + K_;          // 33280 floats

static constexpr float THETA = 0.002f;  // cert threshold; fp16x3 worst error
                                        // (lo*lo drop + accum rounding) < 5.6e-4

typedef _Float16 half8  __attribute__((ext_vector_type(8)));
typedef float    f32x16 __attribute__((ext_vector_type(16)));

// KP: split codebook into fp16 hi/lo, cnorm fp32 + MFMA-fold reorder
// cnA[hi][tile][reg] = cnorm[32*tile + (reg&3)+8*(reg>>2)+4*hi].
// Also zeroes fixcnt (runs before k_assign each replay; graph-safe).
__global__ __launch_bounds__(256) void k_prep(const float* __restrict__ cb,
                                              float* __restrict__ ws) {
    int j = blockIdx.x * 256 + threadIdx.x;   // 0..32767; wave == one cb row
    if (j == 0) ((int*)(ws + WS_FIXCNT))[0] = 0;
    float v = cb[j];
    _Float16 h = (_Float16)v;
    _Float16 lo = (_Float16)(v - (float)h);
    ((_Float16*)(ws + WS_CBH))[j] = h;
    ((_Float16*)(ws + WS_CBL))[j] = lo;
    float sq = v * v;
#pragma unroll
    for (int m = 1; m < 64; m <<= 1) sq += __shfl_xor(sq, m);
    if ((threadIdx.x & 63) == 0) {
        int k = j >> 6;
        ws[WS_CN + k] = sq;
        int t = k >> 5, r5 = k & 31;
        int hi = (r5 >> 2) & 1;
        int reg = (r5 & 3) + 4 * (r5 >> 3);
        ws[WS_CNA + hi * 256 + t * 16 + reg] = sq;
    }
}

// K1: fp16x3 split MFMA assign. R5 post-mortem: per-tile cb fragments came
// from 128B-strided GLOBAL gathers (32 lines/instr, latency junk) and the
// fused stats atomics write-through to HBM (WRITE 68MB at ~0.58TB/s ->
// kernel ran exactly at the write-stream rate, all pipes idle). Fixes:
// (1) NO global atomics: bi written as one plain coalesced int store;
//     stats moved to k_stats (plain-store partials).
// (2) cb tiles staged via LDS double-buffer, T14 async split: issue tile
//     t+1 global->reg before compute(t), ds_write after; 1 barrier/tile.
//     XOR-chunk swizzle (p = chunk ^ (row&7)) makes both the stage writes
//     and the 8 b128 fragment reads exactly 8-round = conflict-optimal.
// LDS 52224B -> 3 blocks/CU (12 waves/CU). MFMA layout/fold identical to
// R5 (numerically validated: passed, absmax 4.9e-4).
__global__ __launch_bounds__(256, 3) void k_assign(const float* __restrict__ x,
                                                   const float* __restrict__ cb,
                                                   float* __restrict__ ws,
                                                   float* __restrict__ out) {
    __shared__ alignas(16) unsigned char smem[52224];
    // [0,16384) xs_h | [16384,32768) xs_l | [32768,49152) cb dbuf (2 x 8KB)
    // [49152,51200) cnA | [51200,51712) bi_s | [51712,52224) cert_s
    // qt epilogue overlays [0,33792) (xs + first KB of cb buf; both dead)
    int* bi_s   = (int*)(smem + 51200);
    int* cert_s = (int*)(smem + 51712);

    const int b    = blockIdx.x;
    const int tid  = threadIdx.x;
    const int lane = tid & 63;
    const int wv   = tid >> 6;
    const int row0 = 2 * b, row1 = 2 * b + 1;
    const int xb0 = (row0 >> 6) * CHW_ + (row0 & 63) * Ww_;
    const int xb1 = (row1 >> 6) * CHW_ + (row1 & 63) * Ww_;

    // ---- stage x -> fp16 hi/lo LDS tile (swizzled; R5-validated) ----
    {
        const int s  = tid & 31;        // token-quad id
        const int c8 = tid >> 5;        // channel octet
        const int r  = s >> 4, wq = s & 15;
        half8 hp[4], lp[4];
#pragma unroll
        for (int stp = 0; stp < 8; ++stp) {
            int ch = c8 * 8 + stp;
            float4 v = *(const float4*)(x + (r ? xb1 : xb0) + ch * HW_ + 4 * wq);
            float vv[4] = {v.x, v.y, v.z, v.w};
#pragma unroll
            for (int j = 0; j < 4; ++j) {
                _Float16 h = (_Float16)vv[j];
                _Float16 lo = (_Float16)(vv[j] - (float)h);
                hp[j][stp] = h; lp[j][stp] = lo;
            }
        }
        const int blk = c8 ^ (wq & 7);
#pragma unroll
        for (int j = 0; j < 4; ++j) {
            int tt = 64 * r + 4 * wq + j;
            *(half8*)(smem + tt * 128 + blk * 16) = hp[j];
            *(half8*)(smem + 16384 + tt * 128 + blk * 16) = lp[j];
        }
        // cnA -> LDS (512 floats)
        ((float*)(smem + 49152))[tid]       = ws[WS_CNA + tid];
        ((float*)(smem + 49152))[tid + 256] = ws[WS_CNA + tid + 256];
    }

    // ---- prologue: stage cb tile 0 into buf0 ----
    const char* cbh_g = (const char*)(ws + WS_CBH);
    const char* cbl_g = (const char*)(ws + WS_CBL);
    {
        float4 h4 = *(const float4*)(cbh_g + tid * 16);
        float4 l4 = *(const float4*)(cbl_g + tid * 16);
        int r = tid >> 3, p = (tid & 7) ^ (r & 7);
        *(float4*)(smem + 32768 + r * 128 + p * 16) = h4;
        *(float4*)(smem + 32768 + 4096 + r * 128 + p * 16) = l4;
    }
    __syncthreads();

    // ---- per-wave B-fragments (x), loaded once ----
    const int tb = 32 * wv + (lane & 31);   // local token of this lane
    const int hi = lane >> 5;
    half8 bh[4], bl[4];
    {
        const int tsw = (tb >> 2) & 7;
#pragma unroll
        for (int ks = 0; ks < 4; ++ks) {
            int blk = (2 * ks + hi) ^ tsw;
            bh[ks] = *(const half8*)(smem + tb * 128 + blk * 16);
            bl[ks] = *(const half8*)(smem + 16384 + tb * 128 + blk * 16);
        }
    }

    // ---- main loop: 16 cw-tiles, cb from LDS dbuf ----
    const float* cnA = (const float*)(smem + 49152);
    const int R = lane & 31;
    float bd1 = __int_as_float(0x7f800000);
    float bd2 = __int_as_float(0x7f800000);
    int bk1 = 0;

#pragma unroll 1
    for (int t = 0; t < 16; ++t) {
        const int cur = t & 1;
        float4 nh, nl;
        if (t < 15) {                    // T14: issue next-tile loads early
            nh = *(const float4*)(cbh_g + (t + 1) * 4096 + tid * 16);
            nl = *(const float4*)(cbl_g + (t + 1) * 4096 + tid * 16);
        }
        const char* cb_b = (const char*)smem + 32768 + cur * 8192;
        half8 ah[4], al[4];
#pragma unroll
        for (int ks = 0; ks < 4; ++ks) {
            int p = (2 * ks + hi) ^ (R & 7);
            ah[ks] = *(const half8*)(cb_b + R * 128 + p * 16);
            al[ks] = *(const half8*)(cb_b + 4096 + R * 128 + p * 16);
        }
        f32x16 acc = {0.f,0.f,0.f,0.f, 0.f,0.f,0.f,0.f,
                      0.f,0.f,0.f,0.f, 0.f,0.f,0.f,0.f};
#pragma unroll
        for (int ks = 0; ks < 4; ++ks) {
            acc = __builtin_amdgcn_mfma_f32_32x32x16_f16(ah[ks], bh[ks], acc, 0, 0, 0);
            acc = __builtin_amdgcn_mfma_f32_32x32x16_f16(ah[ks], bl[ks], acc, 0, 0, 0);
            acc = __builtin_amdgcn_mfma_f32_32x32x16_f16(al[ks], bh[ks], acc, 0, 0, 0);
        }
        float cnv[16];
        {
            const float* cnp = cnA + hi * 256 + t * 16;   // broadcast reads
            *(float4*)&cnv[0]  = *(const float4*)(cnp);
            *(float4*)&cnv[4]  = *(const float4*)(cnp + 4);
            *(float4*)&cnv[8]  = *(const float4*)(cnp + 8);
            *(float4*)&cnv[12] = *(const float4*)(cnp + 12);
        }
        const int tb16 = t << 4;
#pragma unroll
        for (int j = 0; j < 16; ++j) {
            float d = fmaf(-2.0f, acc[j], cnv[j]);
            int kid = tb16 | j;                 // k-order-consistent packed id
            bool lt = d < bd1;
            bd2 = lt ? bd1 : fminf(bd2, d);
            bk1 = lt ? kid : bk1;
            bd1 = fminf(bd1, d);
        }
        if (t < 15) {                    // write prefetched tile to alt buf
            int r = tid >> 3, p2 = (tid & 7) ^ (r & 7);
            char* nb = (char*)smem + 32768 + (cur ^ 1) * 8192;
            *(float4*)(nb + r * 128 + p2 * 16) = nh;
            *(float4*)(nb + 4096 + r * 128 + p2 * 16) = nl;
        }
        __syncthreads();
    }

    // ---- decode + cross-lane (l ^ 32) merge; lanes<32 publish ----
    {
        int t0 = bk1 >> 4, j0 = bk1 & 15;
        int rk = 32 * t0 + (j0 & 3) + 8 * (j0 >> 2) + 4 * hi;
        unsigned uf = __float_as_uint(bd1);
        uf = (uf & 0x80000000u) ? ~uf : (uf | 0x80000000u);
        unsigned long long me = ((unsigned long long)uf << 32) | (unsigned)rk;
        unsigned long long ot = (unsigned long long)__shfl_xor((long long)me, 32);
        float od1 = __shfl_xor(bd1, 32);
        float od2 = __shfl_xor(bd2, 32);
        unsigned long long m1 = (me < ot) ? me : ot;
        float d1m = fminf(bd1, od1);
        float d2m = fminf(fminf(bd2, od2), fmaxf(bd1, od1));
        if (hi == 0) {
            int k1 = (int)(m1 & 0xffffffffu);
            bool cert = (d2m - d1m) > THETA;
            bi_s[tb] = k1;
            cert_s[tb] = cert ? 1 : 0;
            ((int*)(ws + WS_IDX))[128 * b + tb] = k1;   // plain store, no atomic
            if (!cert) {
                int pos = atomicAdd((int*)(ws + WS_FIXCNT), 1);
                ((int*)(ws + WS_FIXLIST))[pos] = 128 * b + tb;   // global token id
            }
        }
    }
    __syncthreads();   // bi_s visible; all LDS reads done

    // ---- q gather + transpose + bulk out write (validated shape) ----
    float (*qt)[132] = (float(*)[132])smem;
#pragma unroll
    for (int jj = 0; jj < 32; ++jj) {
        int tt = wv * 32 + jj;
        qt[lane][tt] = cb[bi_s[tt] * 64 + lane];
    }
    __syncthreads();
#pragma unroll
    for (int r = 0; r < 2; ++r)
#pragma unroll
        for (int j = 0; j < 16; ++j) {
            int c = wv * 16 + j;
            out[(r ? xb1 : xb0) + c * HW_ + lane] = qt[c][64 * r + lane];
        }
}

// KF: exact fp32 rescan for uncertified tokens. Corrects idx (plain store)
// and out BEFORE k_stats consumes idx -> stats need no patching/atomics.
__global__ __launch_bounds__(256) void k_fix(const float* __restrict__ x,
                                             const float* __restrict__ cb,
                                             float* __restrict__ ws,
                                             float* __restrict__ out) {
    __shared__ float xw[4][64];
    const int tid = threadIdx.x, wv = tid >> 6, lane = tid & 63;
    const int cnt = *(const int*)(ws + WS_FIXCNT);
    const int* list = (const int*)(ws + WS_FIXLIST);

    for (int it = blockIdx.x * 4 + wv; it < cnt; it += 256 * 4) {
        int g = list[it];
        int n = g >> 12, hw = g & 4095;
        const float* xp = x + n * CHW_ + hw;
        float xv = xp[lane * HW_];
        xw[wv][lane] = xv;
        unsigned long long best = ~0ull;
#pragma unroll 1
        for (int jj = 0; jj < 8; ++jj) {
            int k = lane + 64 * jj;
            const float4* cr = (const float4*)(cb + k * 64);
            float dot = 0.f;
#pragma unroll
            for (int q = 0; q < 16; ++q) {
                float4 cv = cr[q];
                dot = fmaf(cv.x, xw[wv][4 * q + 0], dot);
                dot = fmaf(cv.y, xw[wv][4 * q + 1], dot);
                dot = fmaf(cv.z, xw[wv][4 * q + 2], dot);
                dot = fmaf(cv.w, xw[wv][4 * q + 3], dot);
            }
            float d = fmaf(-2.0f, dot, ws[WS_CN + k]);
            unsigned uf = __float_as_uint(d);
            uf = (uf & 0x80000000u) ? ~uf : (uf | 0x80000000u);
            unsigned long long cd = ((unsigned long long)uf << 32) | (unsigned)k;
            if (cd < best) best = cd;
        }
#pragma unroll
        for (int m = 1; m < 64; m <<= 1) {
            unsigned long long o = (unsigned long long)__shfl_xor((long long)best, m);
            if (o < best) best = o;
        }
        int k1 = (int)(best & 0xffffffffu);
        out[n * CHW_ + lane * HW_ + hw] = cb[k1 * 64 + lane];
        if (lane == 0) ((int*)(ws + WS_IDX))[g] = k1;
    }
}

// K2: conflict-free LDS-histogram stats (R2-proven access shape) at FIXED
// occupancy: 512 threads (8 waves -> 2/SIMD, vs R3's latency-dead 1/SIMD).
// Block owns TPB contiguous tokens; full psum[512][64] in LDS; per token
// ONE wave-wide ds_add (64 consecutive addrs, 2/bank free, no collisions).
// Writeback = PLAIN coalesced stores to an exclusive partial (34MB at HBM
// rate, NOT the ~0.5TB/s device-atomic rate that capped R4/R5).
__global__ __launch_bounds__(512) void k_stats(const float* __restrict__ x,
                                               const float* __restrict__ ws_ro,
                                               float* __restrict__ ws,
                                               int TPB) {
    __shared__ float psum[512][64];     // 128 KB
    __shared__ float xt[64][65];        // 16.6 KB padded
    __shared__ float pcnt[512];
    __shared__ int   idx_s[512];

    const int tid = threadIdx.x;
    const int bid = blockIdx.x;
    const int wv = tid >> 6, lane = tid & 63;
    const int ngroups = TPB >> 9;
    const int blkbase = bid * TPB;

    const float4 z = make_float4(0.f, 0.f, 0.f, 0.f);
#pragma unroll
    for (int i = 0; i < 16; ++i) ((float4*)psum)[i * 512 + tid] = z;
    if (tid < 512) pcnt[tid] = 0.f;

    const int* __restrict__ idxg = (const int*)ws_ro;   // WS_IDX == 0

    for (int g = 0; g < ngroups; ++g) {
        __syncthreads();   // g=0: zero done; g>0: prev scatter's idx_s reads done
        int k0 = idxg[blkbase + g * 512 + tid];
        idx_s[tid] = k0;
        atomicAdd(&pcnt[k0], 1.0f);     // 512 scattered LDS lane-atomics: cheap

        for (int sc = 0; sc < 8; ++sc) {
            __syncthreads();            // xt free; sc=0 also publishes idx_s
            // stage 64 tokens x 64 ch (coalesced global float4 -> transposed)
#pragma unroll
            for (int it = 0; it < 2; ++it) {
                int e = it * 512 + tid;
                int c = e >> 4, tq = e & 15;
                int tok0 = blkbase + g * 512 + sc * 64;
                int n = tok0 >> 12, hw0 = tok0 & 4095;
                float4 v = *(const float4*)(x + n * CHW_ + c * HW_ + hw0 + 4 * tq);
                xt[4 * tq + 0][c] = v.x;
                xt[4 * tq + 1][c] = v.y;
                xt[4 * tq + 2][c] = v.z;
                xt[4 * tq + 3][c] = v.w;
            }
            __syncthreads();            // xt ready
            // wave wv owns tokens [8wv, 8wv+8): one full-width ds_add each
#pragma unroll
            for (int i = 0; i < 8; ++i) {
                int tok = wv * 8 + i;
                int k = idx_s[sc * 64 + tok];               // wave-uniform
                atomicAdd(&psum[k][lane], xt[tok][lane]);   // 64 consecutive
            }
        }
    }
    __syncthreads();                    // all ds_adds drained

    float* pb = ws + WS_PART + (size_t)bid * SLICE_F;
#pragma unroll
    for (int i = 0; i < 16; ++i)
        ((float4*)pb)[i * 512 + tid] = ((float4*)psum)[i * 512 + tid];
    if (tid < 512) pb[32768 + tid] = pcnt[tid];
}

// K3: reduce P exclusive partials, finalize EMA states + codebook_new.
__global__ __launch_bounds__(256) void k_final(const float* __restrict__ Ns,
                                               const float* __restrict__ ms,
                                               const float* __restrict__ ws,
                                               float* __restrict__ out,
                                               int P) {
    int i = blockIdx.x * 256 + threadIdx.x;   // 0..32767
    int k = i >> 6, c = i & 63;

    const float* base = ws + WS_PART;
    float s = 0.f, cnt = 0.f;
#pragma unroll 8
    for (int p = 0; p < P; ++p) {
        s   += base[(size_t)p * SLICE_F + i];
        cnt += base[(size_t)p * SLICE_F + 32768 + k];
    }

    const float gamma = 0.99f;
    const float omg   = (float)(1.0 - 0.99);

    bool occ = cnt > 0.0f;
    float Nv = Ns[k];
    float Nnew = occ ? (Nv * gamma + cnt * omg) : Nv;

    float mv = ms[i];
    float mnew = occ ? (mv * gamma + s * omg) : mv;

    out[OFF_CB + i] = mnew / Nnew;
    out[OFF_M  + i] = mnew;
    if (c == 0) out[OFF_N + k] = Nnew;
}

extern "C" void kernel_launch(void* const* d_in, const int* in_sizes, int n_in,
                              void* d_out, int out_size, void* d_ws, size_t ws_size,
                              hipStream_t stream) {
    const float* x  = (const float*)d_in[0];
    const float* cb = (const float*)d_in[1];
    const float* Ns = (const float*)d_in[2];
    const float* ms = (const float*)d_in[3];
    float* out = (float*)d_out;
    float* ws  = (float*)d_ws;

    // Partial count from workspace: P=256 needs ~35.3MB; degrade by halving.
    int P = 256;
    while (P > 32 &&
           ((size_t)WS_PART + (size_t)P * SLICE_F) * 4 > ws_size)
        P >>= 1;
    int TPB = T_ / P;

    hipLaunchKernelGGL(k_prep,   dim3(128),  dim3(256), 0, stream, cb, ws);
    hipLaunchKernelGGL(k_assign, dim3(1024), dim3(256), 0, stream, x, cb, ws, out);
    hipLaunchKernelGGL(k_fix,    dim3(256),  dim3(256), 0, stream, x, cb, ws, out);
    hipLaunchKernelGGL(k_stats,  dim3(P),    dim3(512), 0, stream, x, ws, ws, TPB);
    hipLaunchKernelGGL(k_final,  dim3(128),  dim3(256), 0, stream, Ns, ms, ws, out, P);
}

// Round 7
// 190.388 us; speedup vs baseline: 1.3446x; 1.1118x over previous
//
#include <hip/hip_runtime.h>

// Problem constants
static constexpr int Nn_ = 32, Cc_ = 64, Hh_ = 64, Ww_ = 64;
static constexpr int K_ = 512;
static constexpr int HW_ = Hh_ * Ww_;             // 4096
static constexpr int CHW_ = Cc_ * HW_;            // 262144
static constexpr int T_ = Nn_ * Hh_ * Ww_;        // 131072 tokens
static constexpr int OUT_ELEMS = Nn_ * Cc_ * Hh_ * Ww_;  // 8388608
// d_out layout: [out][codebook_new (32768)][N_new (512)][m_new (32768)]
static constexpr int OFF_CB = OUT_ELEMS;
static constexpr int OFF_N  = OUT_ELEMS + 32768;
static constexpr int OFF_M  = OUT_ELEMS + 32768 + 512;

// ws layout (float indices). NO persistent accumulators -> nothing to zero.
// [WS_IDX, +T)        idx per token (int), k_assign writes, k_fix corrects
// [WS_FIXCNT]         fix counter (int, zeroed by k_prep each replay)
// [WS_FIXLIST, +T)    uncertified token ids
// [WS_CBH/CBL]        cb hi/lo fp16 [512][64]
// [WS_CN/CNA]         cnorm fp32 + MFMA-fold reorder
// [WS_PART, P*33280)  P exclusive dense partials [psum 512*64][pcnt 512]
static constexpr int WS_IDX     = 0;
static constexpr int WS_FIXCNT  = T_;                     // 131072
static constexpr int WS_FIXLIST = T_ + 1;                 // 131073
static constexpr int WS_CBH     = 262148;                 // 16B aligned
static constexpr int WS_CBL     = WS_CBH + 16384;         // 278532
static constexpr int WS_CN      = WS_CBL + 16384;         // 294916
static constexpr int WS_CNA     = WS_CN + 512;            // 295428
static constexpr int WS_PART    = 295940;                 // 16B aligned
static constexpr int SLICE_F    = K_ * Cc_ + K_;          // 33280 floats

static constexpr float THETA = 0.002f;  // cert threshold; fp16x3 worst error
                                        // (lo*lo drop + accum rounding) < 5.6e-4

typedef _Float16 half8  __attribute__((ext_vector_type(8)));
typedef float    f32x16 __attribute__((ext_vector_type(16)));

// KP: split codebook into fp16 hi/lo, cnorm fp32 + MFMA-fold reorder
// cnA[hi][tile][reg] = cnorm[32*tile + (reg&3)+8*(reg>>2)+4*hi].
// Also zeroes fixcnt (runs before k_assign each replay; graph-safe).
__global__ __launch_bounds__(256) void k_prep(const float* __restrict__ cb,
                                              float* __restrict__ ws) {
    int j = blockIdx.x * 256 + threadIdx.x;   // 0..32767; wave == one cb row
    if (j == 0) ((int*)(ws + WS_FIXCNT))[0] = 0;
    float v = cb[j];
    _Float16 h = (_Float16)v;
    _Float16 lo = (_Float16)(v - (float)h);
    ((_Float16*)(ws + WS_CBH))[j] = h;
    ((_Float16*)(ws + WS_CBL))[j] = lo;
    float sq = v * v;
#pragma unroll
    for (int m = 1; m < 64; m <<= 1) sq += __shfl_xor(sq, m);
    if ((threadIdx.x & 63) == 0) {
        int k = j >> 6;
        ws[WS_CN + k] = sq;
        int t = k >> 5, r5 = k & 31;
        int hi = (r5 >> 2) & 1;
        int reg = (r5 & 3) + 4 * (r5 >> 3);
        ws[WS_CNA + hi * 256 + t * 16 + reg] = sq;
    }
}

// K1: fp16x3 split MFMA assign (R6-validated, UNCHANGED — the control).
__global__ __launch_bounds__(256, 3) void k_assign(const float* __restrict__ x,
                                                   const float* __restrict__ cb,
                                                   float* __restrict__ ws,
                                                   float* __restrict__ out) {
    __shared__ alignas(16) unsigned char smem[52224];
    // [0,16384) xs_h | [16384,32768) xs_l | [32768,49152) cb dbuf (2 x 8KB)
    // [49152,51200) cnA | [51200,51712) bi_s | [51712,52224) cert_s
    int* bi_s   = (int*)(smem + 51200);
    int* cert_s = (int*)(smem + 51712);

    const int b    = blockIdx.x;
    const int tid  = threadIdx.x;
    const int lane = tid & 63;
    const int wv   = tid >> 6;
    const int row0 = 2 * b, row1 = 2 * b + 1;
    const int xb0 = (row0 >> 6) * CHW_ + (row0 & 63) * Ww_;
    const int xb1 = (row1 >> 6) * CHW_ + (row1 & 63) * Ww_;

    // ---- stage x -> fp16 hi/lo LDS tile (swizzled) ----
    {
        const int s  = tid & 31;        // token-quad id
        const int c8 = tid >> 5;        // channel octet
        const int r  = s >> 4, wq = s & 15;
        half8 hp[4], lp[4];
#pragma unroll
        for (int stp = 0; stp < 8; ++stp) {
            int ch = c8 * 8 + stp;
            float4 v = *(const float4*)(x + (r ? xb1 : xb0) + ch * HW_ + 4 * wq);
            float vv[4] = {v.x, v.y, v.z, v.w};
#pragma unroll
            for (int j = 0; j < 4; ++j) {
                _Float16 h = (_Float16)vv[j];
                _Float16 lo = (_Float16)(vv[j] - (float)h);
                hp[j][stp] = h; lp[j][stp] = lo;
            }
        }
        const int blk = c8 ^ (wq & 7);
#pragma unroll
        for (int j = 0; j < 4; ++j) {
            int tt = 64 * r + 4 * wq + j;
            *(half8*)(smem + tt * 128 + blk * 16) = hp[j];
            *(half8*)(smem + 16384 + tt * 128 + blk * 16) = lp[j];
        }
        ((float*)(smem + 49152))[tid]       = ws[WS_CNA + tid];
        ((float*)(smem + 49152))[tid + 256] = ws[WS_CNA + tid + 256];
    }

    // ---- prologue: stage cb tile 0 into buf0 ----
    const char* cbh_g = (const char*)(ws + WS_CBH);
    const char* cbl_g = (const char*)(ws + WS_CBL);
    {
        float4 h4 = *(const float4*)(cbh_g + tid * 16);
        float4 l4 = *(const float4*)(cbl_g + tid * 16);
        int r = tid >> 3, p = (tid & 7) ^ (r & 7);
        *(float4*)(smem + 32768 + r * 128 + p * 16) = h4;
        *(float4*)(smem + 32768 + 4096 + r * 128 + p * 16) = l4;
    }
    __syncthreads();

    // ---- per-wave B-fragments (x), loaded once ----
    const int tb = 32 * wv + (lane & 31);   // local token of this lane
    const int hi = lane >> 5;
    half8 bh[4], bl[4];
    {
        const int tsw = (tb >> 2) & 7;
#pragma unroll
        for (int ks = 0; ks < 4; ++ks) {
            int blk = (2 * ks + hi) ^ tsw;
            bh[ks] = *(const half8*)(smem + tb * 128 + blk * 16);
            bl[ks] = *(const half8*)(smem + 16384 + tb * 128 + blk * 16);
        }
    }

    // ---- main loop: 16 cw-tiles, cb from LDS dbuf ----
    const float* cnA = (const float*)(smem + 49152);
    const int R = lane & 31;
    float bd1 = __int_as_float(0x7f800000);
    float bd2 = __int_as_float(0x7f800000);
    int bk1 = 0;

#pragma unroll 1
    for (int t = 0; t < 16; ++t) {
        const int cur = t & 1;
        float4 nh, nl;
        if (t < 15) {                    // T14: issue next-tile loads early
            nh = *(const float4*)(cbh_g + (t + 1) * 4096 + tid * 16);
            nl = *(const float4*)(cbl_g + (t + 1) * 4096 + tid * 16);
        }
        const char* cb_b = (const char*)smem + 32768 + cur * 8192;
        half8 ah[4], al[4];
#pragma unroll
        for (int ks = 0; ks < 4; ++ks) {
            int p = (2 * ks + hi) ^ (R & 7);
            ah[ks] = *(const half8*)(cb_b + R * 128 + p * 16);
            al[ks] = *(const half8*)(cb_b + 4096 + R * 128 + p * 16);
        }
        f32x16 acc = {0.f,0.f,0.f,0.f, 0.f,0.f,0.f,0.f,
                      0.f,0.f,0.f,0.f, 0.f,0.f,0.f,0.f};
#pragma unroll
        for (int ks = 0; ks < 4; ++ks) {
            acc = __builtin_amdgcn_mfma_f32_32x32x16_f16(ah[ks], bh[ks], acc, 0, 0, 0);
            acc = __builtin_amdgcn_mfma_f32_32x32x16_f16(ah[ks], bl[ks], acc, 0, 0, 0);
            acc = __builtin_amdgcn_mfma_f32_32x32x16_f16(al[ks], bh[ks], acc, 0, 0, 0);
        }
        float cnv[16];
        {
            const float* cnp = cnA + hi * 256 + t * 16;   // broadcast reads
            *(float4*)&cnv[0]  = *(const float4*)(cnp);
            *(float4*)&cnv[4]  = *(const float4*)(cnp + 4);
            *(float4*)&cnv[8]  = *(const float4*)(cnp + 8);
            *(float4*)&cnv[12] = *(const float4*)(cnp + 12);
        }
        const int tb16 = t << 4;
#pragma unroll
        for (int j = 0; j < 16; ++j) {
            float d = fmaf(-2.0f, acc[j], cnv[j]);
            int kid = tb16 | j;                 // k-order-consistent packed id
            bool lt = d < bd1;
            bd2 = lt ? bd1 : fminf(bd2, d);
            bk1 = lt ? kid : bk1;
            bd1 = fminf(bd1, d);
        }
        if (t < 15) {                    // write prefetched tile to alt buf
            int r = tid >> 3, p2 = (tid & 7) ^ (r & 7);
            char* nb = (char*)smem + 32768 + (cur ^ 1) * 8192;
            *(float4*)(nb + r * 128 + p2 * 16) = nh;
            *(float4*)(nb + 4096 + r * 128 + p2 * 16) = nl;
        }
        __syncthreads();
    }

    // ---- decode + cross-lane (l ^ 32) merge; lanes<32 publish ----
    {
        int t0 = bk1 >> 4, j0 = bk1 & 15;
        int rk = 32 * t0 + (j0 & 3) + 8 * (j0 >> 2) + 4 * hi;
        unsigned uf = __float_as_uint(bd1);
        uf = (uf & 0x80000000u) ? ~uf : (uf | 0x80000000u);
        unsigned long long me = ((unsigned long long)uf << 32) | (unsigned)rk;
        unsigned long long ot = (unsigned long long)__shfl_xor((long long)me, 32);
        float od1 = __shfl_xor(bd1, 32);
        float od2 = __shfl_xor(bd2, 32);
        unsigned long long m1 = (me < ot) ? me : ot;
        float d1m = fminf(bd1, od1);
        float d2m = fminf(fminf(bd2, od2), fmaxf(bd1, od1));
        if (hi == 0) {
            int k1 = (int)(m1 & 0xffffffffu);
            bool cert = (d2m - d1m) > THETA;
            bi_s[tb] = k1;
            cert_s[tb] = cert ? 1 : 0;
            ((int*)(ws + WS_IDX))[128 * b + tb] = k1;   // plain store, no atomic
            if (!cert) {
                int pos = atomicAdd((int*)(ws + WS_FIXCNT), 1);
                ((int*)(ws + WS_FIXLIST))[pos] = 128 * b + tb;   // global token id
            }
        }
    }
    __syncthreads();   // bi_s visible; all LDS reads done

    // ---- q gather + transpose + bulk out write (validated shape) ----
    float (*qt)[132] = (float(*)[132])smem;
#pragma unroll
    for (int jj = 0; jj < 32; ++jj) {
        int tt = wv * 32 + jj;
        qt[lane][tt] = cb[bi_s[tt] * 64 + lane];
    }
    __syncthreads();
#pragma unroll
    for (int r = 0; r < 2; ++r)
#pragma unroll
        for (int j = 0; j < 16; ++j) {
            int c = wv * 16 + j;
            out[(r ? xb1 : xb0) + c * HW_ + lane] = qt[c][64 * r + lane];
        }
}

// KF: exact fp32 rescan for uncertified tokens (R6-validated, unchanged).
__global__ __launch_bounds__(256) void k_fix(const float* __restrict__ x,
                                             const float* __restrict__ cb,
                                             float* __restrict__ ws,
                                             float* __restrict__ out) {
    __shared__ float xw[4][64];
    const int tid = threadIdx.x, wv = tid >> 6, lane = tid & 63;
    const int cnt = *(const int*)(ws + WS_FIXCNT);
    const int* list = (const int*)(ws + WS_FIXLIST);

    for (int it = blockIdx.x * 4 + wv; it < cnt; it += 256 * 4) {
        int g = list[it];
        int n = g >> 12, hw = g & 4095;
        const float* xp = x + n * CHW_ + hw;
        float xv = xp[lane * HW_];
        xw[wv][lane] = xv;
        unsigned long long best = ~0ull;
#pragma unroll 1
        for (int jj = 0; jj < 8; ++jj) {
            int k = lane + 64 * jj;
            const float4* cr = (const float4*)(cb + k * 64);
            float dot = 0.f;
#pragma unroll
            for (int q = 0; q < 16; ++q) {
                float4 cv = cr[q];
                dot = fmaf(cv.x, xw[wv][4 * q + 0], dot);
                dot = fmaf(cv.y, xw[wv][4 * q + 1], dot);
                dot = fmaf(cv.z, xw[wv][4 * q + 2], dot);
                dot = fmaf(cv.w, xw[wv][4 * q + 3], dot);
            }
            float d = fmaf(-2.0f, dot, ws[WS_CN + k]);
            unsigned uf = __float_as_uint(d);
            uf = (uf & 0x80000000u) ? ~uf : (uf | 0x80000000u);
            unsigned long long cd = ((unsigned long long)uf << 32) | (unsigned)k;
            if (cd < best) best = cd;
        }
#pragma unroll
        for (int m = 1; m < 64; m <<= 1) {
            unsigned long long o = (unsigned long long)__shfl_xor((long long)best, m);
            if (o < best) best = o;
        }
        int k1 = (int)(best & 0xffffffffu);
        out[n * CHW_ + lane * HW_ + hw] = cb[k1 * 64 + lane];
        if (lane == 0) ((int*)(ws + WS_IDX))[g] = k1;
    }
}

// K2: one-hot MFMA stats. R6 post-mortem: LDS-histogram version was
// latency-dead (VALUBusy 0.9%, 1 blk/CU at 148KB LDS, barrier-serialized
// load chains). sums[k][c] = onehot[512xT] @ x[Tx64] is a GEMM -> do it on
// the matrix pipe with psum in REGISTERS: 16 waves, wave wv owns k-tile wv
// (32 k) x both c-tiles; acc = 2 x f32x16 = 32 VGPR/lane. No psum LDS, no
// LDS atomics, no zero-init. One-hot A built in-register (8 compares vs
// idx_s) in the HW-validated fragment shape (same instr + layouts as
// k_assign). x hi/lo split (one-hot products exact; fp32-accum rounding
// only). LDS = xt dbuf 32.5KB + idx + pcnt = 37KB; 4 waves/SIMD.
// Writeback: plain stores to exclusive partial (no atomics).
__global__ __launch_bounds__(1024, 4) void k_stats(const float* __restrict__ x,
                                                   const float* __restrict__ ws_ro,
                                                   float* __restrict__ ws,
                                                   int TPB) {
    __shared__ float xt[2][64][65];     // 33280 B, double-buffered
    __shared__ float pcnt[512];
    __shared__ int   idx_s[512];

    const int tid  = threadIdx.x;
    const int bid  = blockIdx.x;
    const int wv   = tid >> 6;          // 0..15 == k-tile
    const int lane = tid & 63;
    const int hi   = lane >> 5;
    const int m    = lane & 31;
    const int NCH  = TPB >> 6;          // 64-token chunks per block

    f32x16 acc0 = {0.f,0.f,0.f,0.f, 0.f,0.f,0.f,0.f,
                   0.f,0.f,0.f,0.f, 0.f,0.f,0.f,0.f};   // c-tile 0
    f32x16 acc1 = acc0;                                  // c-tile 1

    if (tid < 512) pcnt[tid] = 0.f;
    const int* __restrict__ idxg = (const int*)ws_ro;   // WS_IDX == 0

    const int cS = tid >> 4, tq = tid & 15;             // stage mapping
    // prologue: stage chunk 0 into xt[0]
    {
        int tok0 = bid * TPB;
        int n = tok0 >> 12, hw0 = tok0 & 4095;
        float4 v = *(const float4*)(x + n * CHW_ + cS * HW_ + hw0 + 4 * tq);
        xt[0][4 * tq + 0][cS] = v.x;
        xt[0][4 * tq + 1][cS] = v.y;
        xt[0][4 * tq + 2][cS] = v.z;
        xt[0][4 * tq + 3][cS] = v.w;
    }

    int cur = 0;
    int k0 = 0;
    const int kb = (wv << 5) + m;       // this lane's codeword id

#pragma unroll 1
    for (int cc = 0; cc < NCH; ++cc) {
        const bool hasnext = (cc + 1 < NCH);
        float4 v;
        if (hasnext) {                  // T14: issue next-chunk loads early
            int tok0 = bid * TPB + (cc + 1) * 64;
            int n = tok0 >> 12, hw0 = tok0 & 4095;
            v = *(const float4*)(x + n * CHW_ + cS * HW_ + hw0 + 4 * tq);
        }
        if ((cc & 7) == 0 && tid < 512)
            k0 = idxg[bid * TPB + (cc >> 3) * 512 + tid];
        __syncthreads();                // xt[cur] writes + prev idx reads done
        if ((cc & 7) == 0) {
            if (tid < 512) { idx_s[tid] = k0; atomicAdd(&pcnt[k0], 1.0f); }
            __syncthreads();            // idx_s published
        }

        // 4 MFMA steps of 16 tokens each
#pragma unroll
        for (int st = 0; st < 4; ++st) {
            const int t0 = st * 16 + 8 * hi;   // token offset within chunk
            int ii[8];
#pragma unroll
            for (int j = 0; j < 8; ++j)
                ii[j] = idx_s[((cc & 7) << 6) + t0 + j];   // broadcast reads
            half8 bh0, bl0, bh1, bl1;
#pragma unroll
            for (int j = 0; j < 8; ++j) {      // conflict-free: bank=(t0+j+m)%32
                float f0 = xt[cur][t0 + j][m];
                float f1 = xt[cur][t0 + j][32 + m];
                _Float16 h0 = (_Float16)f0;
                _Float16 h1 = (_Float16)f1;
                bh0[j] = h0; bl0[j] = (_Float16)(f0 - (float)h0);
                bh1[j] = h1; bl1[j] = (_Float16)(f1 - (float)h1);
            }
            half8 ah;
#pragma unroll
            for (int j = 0; j < 8; ++j)
                ah[j] = (ii[j] == kb) ? (_Float16)1.0f : (_Float16)0.0f;
            acc0 = __builtin_amdgcn_mfma_f32_32x32x16_f16(ah, bh0, acc0, 0, 0, 0);
            acc0 = __builtin_amdgcn_mfma_f32_32x32x16_f16(ah, bl0, acc0, 0, 0, 0);
            acc1 = __builtin_amdgcn_mfma_f32_32x32x16_f16(ah, bh1, acc1, 0, 0, 0);
            acc1 = __builtin_amdgcn_mfma_f32_32x32x16_f16(ah, bl1, acc1, 0, 0, 0);
        }

        if (hasnext) {                  // write prefetched chunk to alt buf
            xt[cur ^ 1][4 * tq + 0][cS] = v.x;
            xt[cur ^ 1][4 * tq + 1][cS] = v.y;
            xt[cur ^ 1][4 * tq + 2][cS] = v.z;
            xt[cur ^ 1][4 * tq + 3][cS] = v.w;
            cur ^= 1;
        }
    }
    __syncthreads();                    // pcnt atomics drained

    // writeback: exclusive dense partial, plain stores (C-layout decode)
    float* pb = ws + WS_PART + (size_t)bid * SLICE_F;
#pragma unroll
    for (int r = 0; r < 16; ++r) {
        int k = (wv << 5) + (r & 3) + 8 * (r >> 2) + 4 * hi;
        pb[k * 64 + m]      = acc0[r];
        pb[k * 64 + 32 + m] = acc1[r];
    }
    if (tid < 512) pb[32768 + tid] = pcnt[tid];
}

// K3: reduce P exclusive partials, finalize EMA states + codebook_new.
__global__ __launch_bounds__(256) void k_final(const float* __restrict__ Ns,
                                               const float* __restrict__ ms,
                                               const float* __restrict__ ws,
                                               float* __restrict__ out,
                                               int P) {
    int i = blockIdx.x * 256 + threadIdx.x;   // 0..32767
    int k = i >> 6, c = i & 63;

    const float* base = ws + WS_PART;
    float s = 0.f, cnt = 0.f;
#pragma unroll 8
    for (int p = 0; p < P; ++p) {
        s   += base[(size_t)p * SLICE_F + i];
        cnt += base[(size_t)p * SLICE_F + 32768 + k];
    }

    const float gamma = 0.99f;
    const float omg   = (float)(1.0 - 0.99);

    bool occ = cnt > 0.0f;
    float Nv = Ns[k];
    float Nnew = occ ? (Nv * gamma + cnt * omg) : Nv;

    float mv = ms[i];
    float mnew = occ ? (mv * gamma + s * omg) : mv;

    out[OFF_CB + i] = mnew / Nnew;
    out[OFF_M  + i] = mnew;
    if (c == 0) out[OFF_N + k] = Nnew;
}

extern "C" void kernel_launch(void* const* d_in, const int* in_sizes, int n_in,
                              void* d_out, int out_size, void* d_ws, size_t ws_size,
                              hipStream_t stream) {
    const float* x  = (const float*)d_in[0];
    const float* cb = (const float*)d_in[1];
    const float* Ns = (const float*)d_in[2];
    const float* ms = (const float*)d_in[3];
    float* out = (float*)d_out;
    float* ws  = (float*)d_ws;

    // Partial count from workspace: P=256 needs ~35.3MB; degrade by halving.
    int P = 256;
    while (P > 32 &&
           ((size_t)WS_PART + (size_t)P * SLICE_F) * 4 > ws_size)
        P >>= 1;
    int TPB = T_ / P;

    hipLaunchKernelGGL(k_prep,   dim3(128),  dim3(256),  0, stream, cb, ws);
    hipLaunchKernelGGL(k_assign, dim3(1024), dim3(256),  0, stream, x, cb, ws, out);
    hipLaunchKernelGGL(k_fix,    dim3(256),  dim3(256),  0, stream, x, cb, ws, out);
    hipLaunchKernelGGL(k_stats,  dim3(P),    dim3(1024), 0, stream, x, ws, ws, TPB);
    hipLaunchKernelGGL(k_final,  dim3(128),  dim3(256),  0, stream, Ns, ms, ws, out, P);
}

// Round 8
// 181.825 us; speedup vs baseline: 1.4080x; 1.0471x over previous
//
#include <hip/hip_runtime.h>

// Problem constants
static constexpr int Nn_ = 32, Cc_ = 64, Hh_ = 64, Ww_ = 64;
static constexpr int K_ = 512;
static constexpr int HW_ = Hh_ * Ww_;             // 4096
static constexpr int CHW_ = Cc_ * HW_;            // 262144
static constexpr int T_ = Nn_ * Hh_ * Ww_;        // 131072 tokens
static constexpr int OUT_ELEMS = Nn_ * Cc_ * Hh_ * Ww_;  // 8388608
// d_out layout: [out][codebook_new (32768)][N_new (512)][m_new (32768)]
static constexpr int OFF_CB = OUT_ELEMS;
static constexpr int OFF_N  = OUT_ELEMS + 32768;
static constexpr int OFF_M  = OUT_ELEMS + 32768 + 512;

// ws layout (float indices).
// [WS_IDX, +T)        idx per token (int); k_assign writes, k_fix corrects,
//                     k_stats consumes. DEAD afterwards -> pp OVERLAYS it.
// [WS_FIXCNT]         fix counter (int, zeroed by k_prep each replay)
// [WS_FIXLIST, +T)    uncertified token ids (dead after k_fix)
// [WS_PP, +4*33280)   partial-of-partials (k_red out), overlays idx/fixlist
// [WS_CBH/CBL]        cb hi/lo fp16 [512][64]
// [WS_CN/CNA]         cnorm fp32 + MFMA-fold reorder
// [WS_PART, P*33280)  P exclusive dense partials [psum 512*64][pcnt 512]
static constexpr int WS_IDX     = 0;
static constexpr int WS_FIXCNT  = T_;                     // 131072
static constexpr int WS_FIXLIST = T_ + 1;                 // 131073
static constexpr int WS_PP      = 0;                      // overlays dead idx
static constexpr int WS_CBH     = 262148;                 // 16B aligned
static constexpr int WS_CBL     = WS_CBH + 16384;         // 278532
static constexpr int WS_CN      = WS_CBL + 16384;         // 294916
static constexpr int WS_CNA     = WS_CN + 512;            // 295428
static constexpr int WS_PART    = 295940;                 // 16B aligned
static constexpr int SLICE_F    = K_ * Cc_ + K_;          // 33280 floats

static constexpr float THETA = 0.002f;  // cert threshold; fp16x3 worst error
                                        // (lo*lo drop + accum rounding) < 5.6e-4

typedef _Float16 half8  __attribute__((ext_vector_type(8)));
typedef float    f32x16 __attribute__((ext_vector_type(16)));

// KP: split codebook into fp16 hi/lo, cnorm fp32 + MFMA-fold reorder
// cnA[hi][tile][reg] = cnorm[32*tile + (reg&3)+8*(reg>>2)+4*hi].
// Also zeroes fixcnt (runs before k_assign each replay; graph-safe).
__global__ __launch_bounds__(256) void k_prep(const float* __restrict__ cb,
                                              float* __restrict__ ws) {
    int j = blockIdx.x * 256 + threadIdx.x;   // 0..32767; wave == one cb row
    if (j == 0) ((int*)(ws + WS_FIXCNT))[0] = 0;
    float v = cb[j];
    _Float16 h = (_Float16)v;
    _Float16 lo = (_Float16)(v - (float)h);
    ((_Float16*)(ws + WS_CBH))[j] = h;
    ((_Float16*)(ws + WS_CBL))[j] = lo;
    float sq = v * v;
#pragma unroll
    for (int m = 1; m < 64; m <<= 1) sq += __shfl_xor(sq, m);
    if ((threadIdx.x & 63) == 0) {
        int k = j >> 6;
        ws[WS_CN + k] = sq;
        int t = k >> 5, r5 = k & 31;
        int hi = (r5 >> 2) & 1;
        int reg = (r5 & 3) + 4 * (r5 >> 3);
        ws[WS_CNA + hi * 256 + t * 16 + reg] = sq;
    }
}

// K1: fp16x3 split MFMA assign (R6/R7-validated, UNCHANGED — the control).
__global__ __launch_bounds__(256, 3) void k_assign(const float* __restrict__ x,
                                                   const float* __restrict__ cb,
                                                   float* __restrict__ ws,
                                                   float* __restrict__ out) {
    __shared__ alignas(16) unsigned char smem[52224];
    // [0,16384) xs_h | [16384,32768) xs_l | [32768,49152) cb dbuf (2 x 8KB)
    // [49152,51200) cnA | [51200,51712) bi_s | [51712,52224) cert_s
    int* bi_s   = (int*)(smem + 51200);
    int* cert_s = (int*)(smem + 51712);

    const int b    = blockIdx.x;
    const int tid  = threadIdx.x;
    const int lane = tid & 63;
    const int wv   = tid >> 6;
    const int row0 = 2 * b, row1 = 2 * b + 1;
    const int xb0 = (row0 >> 6) * CHW_ + (row0 & 63) * Ww_;
    const int xb1 = (row1 >> 6) * CHW_ + (row1 & 63) * Ww_;

    // ---- stage x -> fp16 hi/lo LDS tile (swizzled) ----
    {
        const int s  = tid & 31;        // token-quad id
        const int c8 = tid >> 5;        // channel octet
        const int r  = s >> 4, wq = s & 15;
        half8 hp[4], lp[4];
#pragma unroll
        for (int stp = 0; stp < 8; ++stp) {
            int ch = c8 * 8 + stp;
            float4 v = *(const float4*)(x + (r ? xb1 : xb0) + ch * HW_ + 4 * wq);
            float vv[4] = {v.x, v.y, v.z, v.w};
#pragma unroll
            for (int j = 0; j < 4; ++j) {
                _Float16 h = (_Float16)vv[j];
                _Float16 lo = (_Float16)(vv[j] - (float)h);
                hp[j][stp] = h; lp[j][stp] = lo;
            }
        }
        const int blk = c8 ^ (wq & 7);
#pragma unroll
        for (int j = 0; j < 4; ++j) {
            int tt = 64 * r + 4 * wq + j;
            *(half8*)(smem + tt * 128 + blk * 16) = hp[j];
            *(half8*)(smem + 16384 + tt * 128 + blk * 16) = lp[j];
        }
        ((float*)(smem + 49152))[tid]       = ws[WS_CNA + tid];
        ((float*)(smem + 49152))[tid + 256] = ws[WS_CNA + tid + 256];
    }

    // ---- prologue: stage cb tile 0 into buf0 ----
    const char* cbh_g = (const char*)(ws + WS_CBH);
    const char* cbl_g = (const char*)(ws + WS_CBL);
    {
        float4 h4 = *(const float4*)(cbh_g + tid * 16);
        float4 l4 = *(const float4*)(cbl_g + tid * 16);
        int r = tid >> 3, p = (tid & 7) ^ (r & 7);
        *(float4*)(smem + 32768 + r * 128 + p * 16) = h4;
        *(float4*)(smem + 32768 + 4096 + r * 128 + p * 16) = l4;
    }
    __syncthreads();

    // ---- per-wave B-fragments (x), loaded once ----
    const int tb = 32 * wv + (lane & 31);   // local token of this lane
    const int hi = lane >> 5;
    half8 bh[4], bl[4];
    {
        const int tsw = (tb >> 2) & 7;
#pragma unroll
        for (int ks = 0; ks < 4; ++ks) {
            int blk = (2 * ks + hi) ^ tsw;
            bh[ks] = *(const half8*)(smem + tb * 128 + blk * 16);
            bl[ks] = *(const half8*)(smem + 16384 + tb * 128 + blk * 16);
        }
    }

    // ---- main loop: 16 cw-tiles, cb from LDS dbuf ----
    const float* cnA = (const float*)(smem + 49152);
    const int R = lane & 31;
    float bd1 = __int_as_float(0x7f800000);
    float bd2 = __int_as_float(0x7f800000);
    int bk1 = 0;

#pragma unroll 1
    for (int t = 0; t < 16; ++t) {
        const int cur = t & 1;
        float4 nh, nl;
        if (t < 15) {                    // T14: issue next-tile loads early
            nh = *(const float4*)(cbh_g + (t + 1) * 4096 + tid * 16);
            nl = *(const float4*)(cbl_g + (t + 1) * 4096 + tid * 16);
        }
        const char* cb_b = (const char*)smem + 32768 + cur * 8192;
        half8 ah[4], al[4];
#pragma unroll
        for (int ks = 0; ks < 4; ++ks) {
            int p = (2 * ks + hi) ^ (R & 7);
            ah[ks] = *(const half8*)(cb_b + R * 128 + p * 16);
            al[ks] = *(const half8*)(cb_b + 4096 + R * 128 + p * 16);
        }
        f32x16 acc = {0.f,0.f,0.f,0.f, 0.f,0.f,0.f,0.f,
                      0.f,0.f,0.f,0.f, 0.f,0.f,0.f,0.f};
#pragma unroll
        for (int ks = 0; ks < 4; ++ks) {
            acc = __builtin_amdgcn_mfma_f32_32x32x16_f16(ah[ks], bh[ks], acc, 0, 0, 0);
            acc = __builtin_amdgcn_mfma_f32_32x32x16_f16(ah[ks], bl[ks], acc, 0, 0, 0);
            acc = __builtin_amdgcn_mfma_f32_32x32x16_f16(al[ks], bh[ks], acc, 0, 0, 0);
        }
        float cnv[16];
        {
            const float* cnp = cnA + hi * 256 + t * 16;   // broadcast reads
            *(float4*)&cnv[0]  = *(const float4*)(cnp);
            *(float4*)&cnv[4]  = *(const float4*)(cnp + 4);
            *(float4*)&cnv[8]  = *(const float4*)(cnp + 8);
            *(float4*)&cnv[12] = *(const float4*)(cnp + 12);
        }
        const int tb16 = t << 4;
#pragma unroll
        for (int j = 0; j < 16; ++j) {
            float d = fmaf(-2.0f, acc[j], cnv[j]);
            int kid = tb16 | j;                 // k-order-consistent packed id
            bool lt = d < bd1;
            bd2 = lt ? bd1 : fminf(bd2, d);
            bk1 = lt ? kid : bk1;
            bd1 = fminf(bd1, d);
        }
        if (t < 15) {                    // write prefetched tile to alt buf
            int r = tid >> 3, p2 = (tid & 7) ^ (r & 7);
            char* nb = (char*)smem + 32768 + (cur ^ 1) * 8192;
            *(float4*)(nb + r * 128 + p2 * 16) = nh;
            *(float4*)(nb + 4096 + r * 128 + p2 * 16) = nl;
        }
        __syncthreads();
    }

    // ---- decode + cross-lane (l ^ 32) merge; lanes<32 publish ----
    {
        int t0 = bk1 >> 4, j0 = bk1 & 15;
        int rk = 32 * t0 + (j0 & 3) + 8 * (j0 >> 2) + 4 * hi;
        unsigned uf = __float_as_uint(bd1);
        uf = (uf & 0x80000000u) ? ~uf : (uf | 0x80000000u);
        unsigned long long me = ((unsigned long long)uf << 32) | (unsigned)rk;
        unsigned long long ot = (unsigned long long)__shfl_xor((long long)me, 32);
        float od1 = __shfl_xor(bd1, 32);
        float od2 = __shfl_xor(bd2, 32);
        unsigned long long m1 = (me < ot) ? me : ot;
        float d1m = fminf(bd1, od1);
        float d2m = fminf(fminf(bd2, od2), fmaxf(bd1, od1));
        if (hi == 0) {
            int k1 = (int)(m1 & 0xffffffffu);
            bool cert = (d2m - d1m) > THETA;
            bi_s[tb] = k1;
            cert_s[tb] = cert ? 1 : 0;
            ((int*)(ws + WS_IDX))[128 * b + tb] = k1;   // plain store, no atomic
            if (!cert) {
                int pos = atomicAdd((int*)(ws + WS_FIXCNT), 1);
                ((int*)(ws + WS_FIXLIST))[pos] = 128 * b + tb;   // global token id
            }
        }
    }
    __syncthreads();   // bi_s visible; all LDS reads done

    // ---- q gather + transpose + bulk out write (validated shape) ----
    float (*qt)[132] = (float(*)[132])smem;
#pragma unroll
    for (int jj = 0; jj < 32; ++jj) {
        int tt = wv * 32 + jj;
        qt[lane][tt] = cb[bi_s[tt] * 64 + lane];
    }
    __syncthreads();
#pragma unroll
    for (int r = 0; r < 2; ++r)
#pragma unroll
        for (int j = 0; j < 16; ++j) {
            int c = wv * 16 + j;
            out[(r ? xb1 : xb0) + c * HW_ + lane] = qt[c][64 * r + lane];
        }
}

// KF: exact fp32 rescan for uncertified tokens (R6-validated, unchanged).
__global__ __launch_bounds__(256) void k_fix(const float* __restrict__ x,
                                             const float* __restrict__ cb,
                                             float* __restrict__ ws,
                                             float* __restrict__ out) {
    __shared__ float xw[4][64];
    const int tid = threadIdx.x, wv = tid >> 6, lane = tid & 63;
    const int cnt = *(const int*)(ws + WS_FIXCNT);
    const int* list = (const int*)(ws + WS_FIXLIST);

    for (int it = blockIdx.x * 4 + wv; it < cnt; it += 256 * 4) {
        int g = list[it];
        int n = g >> 12, hw = g & 4095;
        const float* xp = x + n * CHW_ + hw;
        float xv = xp[lane * HW_];
        xw[wv][lane] = xv;
        unsigned long long best = ~0ull;
#pragma unroll 1
        for (int jj = 0; jj < 8; ++jj) {
            int k = lane + 64 * jj;
            const float4* cr = (const float4*)(cb + k * 64);
            float dot = 0.f;
#pragma unroll
            for (int q = 0; q < 16; ++q) {
                float4 cv = cr[q];
                dot = fmaf(cv.x, xw[wv][4 * q + 0], dot);
                dot = fmaf(cv.y, xw[wv][4 * q + 1], dot);
                dot = fmaf(cv.z, xw[wv][4 * q + 2], dot);
                dot = fmaf(cv.w, xw[wv][4 * q + 3], dot);
            }
            float d = fmaf(-2.0f, dot, ws[WS_CN + k]);
            unsigned uf = __float_as_uint(d);
            uf = (uf & 0x80000000u) ? ~uf : (uf | 0x80000000u);
            unsigned long long cd = ((unsigned long long)uf << 32) | (unsigned)k;
            if (cd < best) best = cd;
        }
#pragma unroll
        for (int m = 1; m < 64; m <<= 1) {
            unsigned long long o = (unsigned long long)__shfl_xor((long long)best, m);
            if (o < best) best = o;
        }
        int k1 = (int)(best & 0xffffffffu);
        out[n * CHW_ + lane * HW_ + hw] = cb[k1 * 64 + lane];
        if (lane == 0) ((int*)(ws + WS_IDX))[g] = k1;
    }
}

// K2: one-hot MFMA stats (R7-validated, unchanged).
__global__ __launch_bounds__(1024, 4) void k_stats(const float* __restrict__ x,
                                                   const float* __restrict__ ws_ro,
                                                   float* __restrict__ ws,
                                                   int TPB) {
    __shared__ float xt[2][64][65];     // 33280 B, double-buffered
    __shared__ float pcnt[512];
    __shared__ int   idx_s[512];

    const int tid  = threadIdx.x;
    const int bid  = blockIdx.x;
    const int wv   = tid >> 6;          // 0..15 == k-tile
    const int lane = tid & 63;
    const int hi   = lane >> 5;
    const int m    = lane & 31;
    const int NCH  = TPB >> 6;          // 64-token chunks per block

    f32x16 acc0 = {0.f,0.f,0.f,0.f, 0.f,0.f,0.f,0.f,
                   0.f,0.f,0.f,0.f, 0.f,0.f,0.f,0.f};   // c-tile 0
    f32x16 acc1 = acc0;                                  // c-tile 1

    if (tid < 512) pcnt[tid] = 0.f;
    const int* __restrict__ idxg = (const int*)ws_ro;   // WS_IDX == 0

    const int cS = tid >> 4, tq = tid & 15;             // stage mapping
    // prologue: stage chunk 0 into xt[0]
    {
        int tok0 = bid * TPB;
        int n = tok0 >> 12, hw0 = tok0 & 4095;
        float4 v = *(const float4*)(x + n * CHW_ + cS * HW_ + hw0 + 4 * tq);
        xt[0][4 * tq + 0][cS] = v.x;
        xt[0][4 * tq + 1][cS] = v.y;
        xt[0][4 * tq + 2][cS] = v.z;
        xt[0][4 * tq + 3][cS] = v.w;
    }

    int cur = 0;
    int k0 = 0;
    const int kb = (wv << 5) + m;       // this lane's codeword id

#pragma unroll 1
    for (int cc = 0; cc < NCH; ++cc) {
        const bool hasnext = (cc + 1 < NCH);
        float4 v;
        if (hasnext) {                  // T14: issue next-chunk loads early
            int tok0 = bid * TPB + (cc + 1) * 64;
            int n = tok0 >> 12, hw0 = tok0 & 4095;
            v = *(const float4*)(x + n * CHW_ + cS * HW_ + hw0 + 4 * tq);
        }
        if ((cc & 7) == 0 && tid < 512)
            k0 = idxg[bid * TPB + (cc >> 3) * 512 + tid];
        __syncthreads();                // xt[cur] writes + prev idx reads done
        if ((cc & 7) == 0) {
            if (tid < 512) { idx_s[tid] = k0; atomicAdd(&pcnt[k0], 1.0f); }
            __syncthreads();            // idx_s published
        }

        // 4 MFMA steps of 16 tokens each
#pragma unroll
        for (int st = 0; st < 4; ++st) {
            const int t0 = st * 16 + 8 * hi;   // token offset within chunk
            int ii[8];
#pragma unroll
            for (int j = 0; j < 8; ++j)
                ii[j] = idx_s[((cc & 7) << 6) + t0 + j];   // broadcast reads
            half8 bh0, bl0, bh1, bl1;
#pragma unroll
            for (int j = 0; j < 8; ++j) {      // conflict-free: bank=(t0+j+m)%32
                float f0 = xt[cur][t0 + j][m];
                float f1 = xt[cur][t0 + j][32 + m];
                _Float16 h0 = (_Float16)f0;
                _Float16 h1 = (_Float16)f1;
                bh0[j] = h0; bl0[j] = (_Float16)(f0 - (float)h0);
                bh1[j] = h1; bl1[j] = (_Float16)(f1 - (float)h1);
            }
            half8 ah;
#pragma unroll
            for (int j = 0; j < 8; ++j)
                ah[j] = (ii[j] == kb) ? (_Float16)1.0f : (_Float16)0.0f;
            acc0 = __builtin_amdgcn_mfma_f32_32x32x16_f16(ah, bh0, acc0, 0, 0, 0);
            acc0 = __builtin_amdgcn_mfma_f32_32x32x16_f16(ah, bl0, acc0, 0, 0, 0);
            acc1 = __builtin_amdgcn_mfma_f32_32x32x16_f16(ah, bh1, acc1, 0, 0, 0);
            acc1 = __builtin_amdgcn_mfma_f32_32x32x16_f16(ah, bl1, acc1, 0, 0, 0);
        }

        if (hasnext) {                  // write prefetched chunk to alt buf
            xt[cur ^ 1][4 * tq + 0][cS] = v.x;
            xt[cur ^ 1][4 * tq + 1][cS] = v.y;
            xt[cur ^ 1][4 * tq + 2][cS] = v.z;
            xt[cur ^ 1][4 * tq + 3][cS] = v.w;
            cur ^= 1;
        }
    }
    __syncthreads();                    // pcnt atomics drained

    // writeback: exclusive dense partial, plain stores (C-layout decode)
    float* pb = ws + WS_PART + (size_t)bid * SLICE_F;
#pragma unroll
    for (int r = 0; r < 16; ++r) {
        int k = (wv << 5) + (r & 3) + 8 * (r >> 2) + 4 * hi;
        pb[k * 64 + m]      = acc0[r];
        pb[k * 64 + 32 + m] = acc1[r];
    }
    if (tid < 512) pb[32768 + tid] = pcnt[tid];
}

// KR: stage-1 reduction. R7 post-mortem: single-stage k_final read 34MB with
// 128 blocks (1 wave/SIMD) -> latency-exposed ~0.8TB/s -> ~40us (hidden
// under the top-5 cut; isolated via R6/R7 cross-round accounting). Here:
// grid (130 x 4 groups) = 520 blocks (2/CU, 8 waves/CU), each sums P/4
// partials for 256 contiguous elems of the flat 33280-slice (psum+pcnt
// together). Fully coalesced; ~4-6TB/s -> ~7us. pp overlays the DEAD
// idx/fixlist region (k_stats was idx's last consumer) so the P=256
// workspace budget is untouched.
__global__ __launch_bounds__(256) void k_red(const float* __restrict__ ws_ro,
                                             float* __restrict__ ws,
                                             int PG) {
    const int i = blockIdx.x * 256 + threadIdx.x;   // 0..33279 (130*256 exact)
    const int g = blockIdx.y;                       // 0..3
    const float* base = ws_ro + WS_PART + (size_t)g * PG * SLICE_F;
    float s = 0.f;
#pragma unroll 8
    for (int p = 0; p < PG; ++p)
        s += base[(size_t)p * SLICE_F + i];
    ws[WS_PP + g * SLICE_F + i] = s;
}

// K3: finalize from the 4 L2-hot pp slices (532KB).
__global__ __launch_bounds__(256) void k_final(const float* __restrict__ Ns,
                                               const float* __restrict__ ms,
                                               const float* __restrict__ ws,
                                               float* __restrict__ out) {
    int i = blockIdx.x * 256 + threadIdx.x;   // 0..32767
    int k = i >> 6, c = i & 63;

    const float* pp = ws + WS_PP;
    float s = 0.f, cnt = 0.f;
#pragma unroll
    for (int g = 0; g < 4; ++g) {
        s   += pp[g * SLICE_F + i];
        cnt += pp[g * SLICE_F + 32768 + k];
    }

    const float gamma = 0.99f;
    const float omg   = (float)(1.0 - 0.99);

    bool occ = cnt > 0.0f;
    float Nv = Ns[k];
    float Nnew = occ ? (Nv * gamma + cnt * omg) : Nv;

    float mv = ms[i];
    float mnew = occ ? (mv * gamma + s * omg) : mv;

    out[OFF_CB + i] = mnew / Nnew;
    out[OFF_M  + i] = mnew;
    if (c == 0) out[OFF_N + k] = Nnew;
}

extern "C" void kernel_launch(void* const* d_in, const int* in_sizes, int n_in,
                              void* d_out, int out_size, void* d_ws, size_t ws_size,
                              hipStream_t stream) {
    const float* x  = (const float*)d_in[0];
    const float* cb = (const float*)d_in[1];
    const float* Ns = (const float*)d_in[2];
    const float* ms = (const float*)d_in[3];
    float* out = (float*)d_out;
    float* ws  = (float*)d_ws;

    // Partial count from workspace: P=256 needs ~35.3MB; degrade by halving.
    int P = 256;
    while (P > 32 &&
           ((size_t)WS_PART + (size_t)P * SLICE_F) * 4 > ws_size)
        P >>= 1;
    int TPB = T_ / P;
    int PG  = P / 4;

    hipLaunchKernelGGL(k_prep,   dim3(128),     dim3(256),  0, stream, cb, ws);
    hipLaunchKernelGGL(k_assign, dim3(1024),    dim3(256),  0, stream, x, cb, ws, out);
    hipLaunchKernelGGL(k_fix,    dim3(256),     dim3(256),  0, stream, x, cb, ws, out);
    hipLaunchKernelGGL(k_stats,  dim3(P),       dim3(1024), 0, stream, x, ws, ws, TPB);
    hipLaunchKernelGGL(k_red,    dim3(130, 4),  dim3(256),  0, stream, ws, ws, PG);
    hipLaunchKernelGGL(k_final,  dim3(128),     dim3(256),  0, stream, Ns, ms, ws, out);
}